// Round 13
// baseline (363.518 us; speedup 1.0000x reference)
//
#include <hip/hip_runtime.h>
#include <stdint.h>

// ---------------------------------------------------------------------------
// GNN layer, MI355X (gfx950). All GEMMs via v_mfma_f32_32x32x16_f16, fp32 acc.
// Transposed formulation: C^T[out][edge] = W^T[out][k] @ feats^T[k][edge].
// Each wave owns 32 edges (cols) x full output width (8 or 4 32-row m-frags).
// Inter-layer activation handoff in registers via cvt_pkrtz + permlane32_swap.
//
// Round 13: T4 counted-vmcnt pipeline. 3-buffer LDS rotation (gc % 3),
// 1-tile phases, stage distance 2. Each phase ends with
// s_waitcnt vmcnt(N) + sched_barrier(0) + raw s_barrier, N = loads issued in
// THAT phase -> previous phase's stages drain, this phase's prefetch stays in
// flight across the barrier (removes the vmcnt(0) drain __syncthreads forces).
// Derivation (per-wave, oldest-first drain): entering any phase outstanding
// <= c_prev; phase issues c_t; wait vmcnt(c_t) drains exactly the c_prev
// oldest = previous phase's stages. WAR safe: buffer reuse distance 3 > stage
// distance 2; ds_reads are register-consumed before each barrier.
// GEMM1 back to Kp=288 (9 tiles, odd KT now fine). Address algebra
// (stage_tile/ldsA/buildB) byte-identical to round 12 (proven, 340us).
// ---------------------------------------------------------------------------

typedef _Float16 h16;
typedef _Float16 half8  __attribute__((ext_vector_type(8)));
typedef _Float16 h16x2  __attribute__((ext_vector_type(2)));
typedef float    f32x16 __attribute__((ext_vector_type(16)));
typedef unsigned u32x4  __attribute__((ext_vector_type(4)));

__device__ __forceinline__ f32x16 MFMA(half8 a, half8 b, f32x16 c) {
  return __builtin_amdgcn_mfma_f32_32x32x16_f16(a, b, c, 0, 0, 0);
}

// v_permlane32_swap_b32: new_a = [a_lo | b_lo], new_b = [a_hi | b_hi]
__device__ __forceinline__ void lane_swap(unsigned &a, unsigned &b) {
  asm volatile("v_permlane32_swap_b32 %0, %1" : "+v"(a), "+v"(b));
}

// order-preserving float->uint map (atomicMax-able), init = 0
__device__ __forceinline__ unsigned ordf(float f) {
  unsigned b = __float_as_uint(f);
  return (b & 0x80000000u) ? ~b : (b | 0x80000000u);
}
__device__ __forceinline__ float ordinv(unsigned u) {
  return __uint_as_float((u & 0x80000000u) ? (u ^ 0x80000000u) : ~u);
}

// Counted-vmcnt phase boundary: wait for all but the newest N vmem ops, then
// block barrier. "memory" clobber + sched_barrier(0) pin memory ops.
template<int N>
__device__ __forceinline__ void phase_sync() {
  if constexpr (N >= 8)      asm volatile("s_waitcnt vmcnt(8)" ::: "memory");
  else if constexpr (N == 6) asm volatile("s_waitcnt vmcnt(6)" ::: "memory");
  else if constexpr (N == 4) asm volatile("s_waitcnt vmcnt(4)" ::: "memory");
  else if constexpr (N == 2) asm volatile("s_waitcnt vmcnt(2)" ::: "memory");
  else                       asm volatile("s_waitcnt vmcnt(0)" ::: "memory");
  __builtin_amdgcn_sched_barrier(0);
  __builtin_amdgcn_s_barrier();
}

// Stage one weight tile [R=32*MFA rows][32 k] f16 into LDS via global_load_lds.
// LDS layout: row-major 64B rows, 16B chunk index XOR-swizzled with (row>>1)&3
// (pre-swizzled on the GLOBAL source; LDS dest stays linear per G21).
// Per wave: MFA/2 global_load_lds ops (4 for MFA=8, 2 for MFA=4).
template<int MFA, int WAVES>
__device__ __forceinline__ void stage_tile(h16* dst, const h16* wT, int K, int kt, int tid) {
  int wv = tid >> 6, lane = tid & 63;
  static_assert((MFA * 2) % WAVES == 0, "tile chunks must divide evenly");
#pragma unroll
  for (int it = 0; it < (MFA * 2) / WAVES; ++it) {
    int slotbase = it * (WAVES * 64) + wv * 64;  // wave-uniform
    int s = slotbase + lane;
    int row = s >> 2, x = s & 3;
    int c = x ^ ((row >> 1) & 3);
    const h16* src = wT + (size_t)row * K + kt * 32 + c * 8;
    h16* d = dst + slotbase * 8;                 // wave-uniform base; lane*16B implicit
    __builtin_amdgcn_global_load_lds((const __attribute__((address_space(1))) unsigned*)src,
                                     (__attribute__((address_space(3))) unsigned*)d, 16, 0, 0);
  }
}

// A-frag read: lane holds W^T[32*mf + (lane&31)][16*ksl + 8*(lane>>5) + i]
__device__ __forceinline__ half8 ldsA(const h16* buf, int mf, int ksl, int lane) {
  int r31 = lane & 31, g = lane >> 5;
  int c = (2 * ksl + g) ^ ((r31 >> 1) & 3);
  return *(const half8*)(buf + mf * 1024 + r31 * 32 + c * 8);
}

// acc(16 f32, D-layout row=(r&3)+8*(r>>2)+4g) + bias [-> relu] -> 8x packed f16
template<bool RELU>
__device__ __forceinline__ void pack_frag(unsigned* hr, const f32x16 a, const float* bias, int g) {
#pragma unroll
  for (int j = 0; j < 8; ++j) {
    int m = 2 * (j & 1) + 8 * (j >> 1) + 4 * g;
    float x = a[2 * j]     + bias[m];
    float y = a[2 * j + 1] + bias[m + 1];
    if (RELU) { x = fmaxf(x, 0.f); y = fmaxf(y, 0.f); }
    auto p = __builtin_amdgcn_cvt_pkrtz(x, y);
    hr[j] = __builtin_bit_cast(unsigned, p);
  }
}

// Build next-GEMM B-frag (k = 16*ks + 8g + i) from packed hregs of this K-tile.
// swap(v_p, u_p) -> (B[p], B[p+2]); ks = 2*kt + ksl, v_p=hr[4ksl+p], u_p=hr[4ksl+2+p]
__device__ __forceinline__ half8 buildB(unsigned* hr, int ksl) {
  unsigned v0 = hr[4 * ksl + 0], v1 = hr[4 * ksl + 1];
  unsigned u0 = hr[4 * ksl + 2], u1 = hr[4 * ksl + 3];
  lane_swap(v0, u0);
  lane_swap(v1, u1);
  u32x4 t = {v0, v1, u0, u1};
  return __builtin_bit_cast(half8, t);
}

// Generic GEMM with B from hregs; 3-buffer rotation, 1-tile phases, counted
// vmcnt. GB = global tile counter base; buffer = gc % 3. Stages next GEMM's
// tiles 0,1 in the last two phases (into (GB+KT)%3, (GB+KT+1)%3).
template<int MFA, int KT, int GB, int NMFA, int WAVES>
__device__ __forceinline__ void gemm_hregB3(f32x16* acc, unsigned (*hreg)[8],
    const h16* wT, int K, const h16* nW, int nK,
    h16 (*wbuf)[8192], int tid, int lane) {
#pragma unroll
  for (int t = 0; t < KT; ++t) {
    if (t + 2 < KT)
      stage_tile<MFA, WAVES>(wbuf[(GB + t + 2) % 3], wT, K, t + 2, tid);
    else if (nW != nullptr)
      stage_tile<NMFA, WAVES>(wbuf[(GB + t + 2) % 3], nW, nK, t + 2 - KT, tid);
    const h16* rb = wbuf[(GB + t) % 3];
    __builtin_amdgcn_s_setprio(1);
#pragma unroll
    for (int ksl = 0; ksl < 2; ++ksl) {
      half8 b = buildB(hreg[t], ksl);
#pragma unroll
      for (int mf = 0; mf < MFA; ++mf)
        acc[mf] = MFMA(ldsA(rb, mf, ksl, lane), b, acc[mf]);
    }
    __builtin_amdgcn_s_setprio(0);
    if (t + 2 < KT)          phase_sync<MFA / 2>();
    else if (nW != nullptr)  phase_sync<NMFA / 2>();
    else                     phase_sync<0>();
  }
}

// ---------------------------------------------------------------------------
// Edge kernel: feats(272->pad 288) -> msg MLP -> msgs(128) -> gate MLP -> gate
// 256 threads = 4 waves x 32 edges = 128 edges/block.
// Global tile counters: GEMM1 w1t 0..8, GEMM2 w2t 9..16, GEMM3 w3t 17..24,
// GEMM4 a1t 25..28, GEMM5 a2t 29..32. Buffer = gc % 3.
// ---------------------------------------------------------------------------
__global__ __launch_bounds__(256, 2) void k_edge(
    const h16* __restrict__ nodes_h, const h16* __restrict__ edges_h,
    const int* __restrict__ senders, const int* __restrict__ receivers,
    const int* __restrict__ starts, const int* __restrict__ rank,
    const h16* __restrict__ w1t, const h16* __restrict__ w2t, const h16* __restrict__ w3t,
    const h16* __restrict__ a1t, const h16* __restrict__ a2t,
    const float* __restrict__ b1, const float* __restrict__ b2, const float* __restrict__ b3,
    const float* __restrict__ ab1, const float* __restrict__ ab2,
    const float* __restrict__ ag3, const float* __restrict__ ab3,
    h16* __restrict__ msgs_h, float* __restrict__ gate, unsigned* __restrict__ segmax, int E)
{
  __shared__ h16 wbuf[3][8192];   // 3 x 16KB weight tiles (1 compute, 2 staging)
  __shared__ float sb[1025];      // biases + ag_w3

  int tid = threadIdx.x, lane = tid & 63, wv = tid >> 6;
  int g = lane >> 5, c31 = lane & 31;

  sb[tid] = b1[tid];
  sb[256 + tid] = b2[tid];
  if (tid < 128) {
    sb[512 + tid] = b3[tid];
    sb[640 + tid] = ab1[tid];
    sb[768 + tid] = ab2[tid];
    sb[896 + tid] = ag3[tid];
  }
  if (tid == 0) sb[1024] = ab3[0];

  int e = blockIdx.x * 128 + wv * 32 + c31;
  bool ev = (e < E);
  int ec = ev ? e : (E - 1);
  int se = senders[ec], re = receivers[ec];
  int pidx = starts[re] + rank[ec];   // CSR slot (rank from prep's histogram)
  const h16* pe = edges_h + (size_t)ec * 16;
  const h16* ps = nodes_h + (size_t)se * 128;
  const h16* pr = nodes_h + (size_t)re * 128;

  // feats^T B-frag, 16-wide slice ks: 0=edge, 1..8=sender, 9..16=receiver, 17=pad
  auto loadB1 = [&](int ks) -> half8 {
    if (ks >= 17) { half8 z = {}; return z; }
    const h16* base = (ks == 0) ? pe : (ks < 9) ? (ps + 16 * ks - 16) : (pr + 16 * ks - 144);
    return *(const half8*)(base + 8 * g);
  };

  // prologue: stage w1t tiles 0,1 (gc 0,1 -> bufs 0,1); load B slices 0..3.
  // 12 vmem/wave issued; vmcnt(8) drains tile0's 4 stages.
  stage_tile<8, 4>(wbuf[0], w1t, 288, 0, tid);
  stage_tile<8, 4>(wbuf[1], w1t, 288, 1, tid);
  half8 bq0 = loadB1(0), bq1 = loadB1(1);
  half8 bm0 = loadB1(2), bm1 = loadB1(3);
  half8 bn0 = {}, bn1 = {};
  phase_sync<8>();

  // ---- GEMM1: h1^T[256][32e] = W1^T @ feats^T, Kp=288 (9 tiles, gc 0..8)
  f32x16 acc1[8];
#pragma unroll
  for (int i = 0; i < 8; ++i) acc1[i] = f32x16{};
#pragma unroll
  for (int t = 0; t < 9; ++t) {
    if (t + 2 < 9) {
      stage_tile<8, 4>(wbuf[(t + 2) % 3], w1t, 288, t + 2, tid);
      bn0 = loadB1(2 * t + 4);
      bn1 = loadB1(2 * t + 5);
    } else {
      stage_tile<8, 4>(wbuf[(t + 2) % 3], w2t, 256, t - 7, tid);  // gc 9,10
    }
    const h16* rb = wbuf[t % 3];
    __builtin_amdgcn_s_setprio(1);
#pragma unroll
    for (int mf = 0; mf < 8; ++mf) acc1[mf] = MFMA(ldsA(rb, mf, 0, lane), bq0, acc1[mf]);
#pragma unroll
    for (int mf = 0; mf < 8; ++mf) acc1[mf] = MFMA(ldsA(rb, mf, 1, lane), bq1, acc1[mf]);
    __builtin_amdgcn_s_setprio(0);
    bq0 = bm0; bq1 = bm1; bm0 = bn0; bm1 = bn1;
    if (t + 2 < 9) phase_sync<6>();   // 4 stage + 2 B this phase
    else           phase_sync<4>();   // 4 stage only
  }
  unsigned hreg1[8][8];
#pragma unroll
  for (int mf = 0; mf < 8; ++mf) pack_frag<true>(hreg1[mf], acc1[mf], sb + 32 * mf, g);

  // ---- GEMM2: h2^T = W2^T @ h1^T, K=256 (gc 9..16)
  f32x16 acc2[8];
#pragma unroll
  for (int i = 0; i < 8; ++i) acc2[i] = f32x16{};
  gemm_hregB3<8, 8, 9, 4, 4>(acc2, hreg1, w2t, 256, w3t, 256, wbuf, tid, lane);
  unsigned hreg2[8][8];
#pragma unroll
  for (int mf = 0; mf < 8; ++mf) pack_frag<false>(hreg2[mf], acc2[mf], sb + 256 + 32 * mf, g);

  // ---- GEMM3: msgs^T[128][32e] = W3^T @ h2^T, K=256 (gc 17..24)
  f32x16 acc3[4];
#pragma unroll
  for (int i = 0; i < 4; ++i) acc3[i] = f32x16{};
  gemm_hregB3<4, 8, 17, 4, 4>(acc3, hreg2, w3t, 256, a1t, 128, wbuf, tid, lane);
  unsigned hreg3[4][8];
  unsigned* mrow = (unsigned*)(msgs_h + (size_t)pidx * 128);
#pragma unroll
  for (int mf = 0; mf < 4; ++mf) {
    pack_frag<false>(hreg3[mf], acc3[mf], sb + 512 + 32 * mf, g);
    if (ev) {
#pragma unroll
      for (int j = 0; j < 8; ++j)
        mrow[16 * mf + (j & 1) + 4 * (j >> 1) + 2 * g] = hreg3[mf][j];
    }
  }

  // ---- GEMM4: g1^T = Ag1^T @ msgs^T, K=128 (gc 25..28)
  f32x16 acc4[4];
#pragma unroll
  for (int i = 0; i < 4; ++i) acc4[i] = f32x16{};
  gemm_hregB3<4, 4, 25, 4, 4>(acc4, hreg3, a1t, 128, a2t, 128, wbuf, tid, lane);
  unsigned hreg4[4][8];
#pragma unroll
  for (int mf = 0; mf < 4; ++mf) pack_frag<true>(hreg4[mf], acc4[mf], sb + 640 + 32 * mf, g);

  // ---- GEMM5: g2^T = Ag2^T @ g1^T, K=128 (gc 29..32)
  f32x16 acc5[4];
#pragma unroll
  for (int i = 0; i < 4; ++i) acc5[i] = f32x16{};
  gemm_hregB3<4, 4, 29, 4, 4>(acc5, hreg4, a2t, 128, (const h16*)nullptr, 0, wbuf, tid, lane);

  // ---- gate = (g2 + ab2) . ag_w3 + ab3, stored at pidx
  float gs = 0.f;
#pragma unroll
  for (int mf = 0; mf < 4; ++mf)
#pragma unroll
    for (int r = 0; r < 16; ++r) {
      int m = 32 * mf + (r & 3) + 8 * (r >> 2) + 4 * g;
      gs += (acc5[mf][r] + sb[768 + m]) * sb[896 + m];
    }
  unsigned xa = __float_as_uint(gs), xb = xa;
  lane_swap(xa, xb);  // xa = lo-half gs for all, xb = hi-half gs for all
  float tot = __uint_as_float(xa) + __uint_as_float(xb) + sb[1024];
  if (lane < 32 && ev) {
    gate[pidx] = tot;
    atomicMax(segmax + re, ordf(tot));
  }
}

// ---------------------------------------------------------------------------
// Update kernel: [nodes | aggr](256) -> update MLP -> out(128) fp32
// 256 threads = 4 waves x 32 nodes = 128 nodes/block.
// Global tile counters: GEMM1 u1t 0..7, GEMM2 u2t 8..15, GEMM3 u3t 16..23.
// ---------------------------------------------------------------------------
__global__ __launch_bounds__(256, 2) void k_update(
    const h16* __restrict__ nodes_h, const h16* __restrict__ aggr_h,
    const h16* __restrict__ u1t, const h16* __restrict__ u2t, const h16* __restrict__ u3t,
    const float* __restrict__ b1, const float* __restrict__ b2, const float* __restrict__ b3,
    float* __restrict__ out, int N)
{
  __shared__ h16 wbuf[3][8192];
  __shared__ float sb[640];
  int tid = threadIdx.x, lane = tid & 63, wv = tid >> 6;
  int g = lane >> 5, c31 = lane & 31;
  sb[tid] = b1[tid];
  sb[256 + tid] = b2[tid];
  if (tid < 128) sb[512 + tid] = b3[tid];

  int n = blockIdx.x * 128 + wv * 32 + c31;
  int nc = (n < N) ? n : (N - 1);
  const h16* pn = nodes_h + (size_t)nc * 128;
  const h16* pa = aggr_h + (size_t)nc * 128;
  auto loadB = [&](int ks) -> half8 {
    const h16* base = (ks < 8) ? (pn + 16 * ks) : (pa + 16 * ks - 128);
    return *(const half8*)(base + 8 * g);
  };

  // prologue: stage u1t tiles 0,1 (gc 0,1 -> bufs 0,1); B slices 0..3
  stage_tile<8, 4>(wbuf[0], u1t, 256, 0, tid);
  stage_tile<8, 4>(wbuf[1], u1t, 256, 1, tid);
  half8 bq0 = loadB(0), bq1 = loadB(1);
  half8 bm0 = loadB(2), bm1 = loadB(3);
  half8 bn0 = {}, bn1 = {};
  phase_sync<8>();

  // ---- GEMM1: K=256 (8 tiles, gc 0..7)
  f32x16 acc1[8];
#pragma unroll
  for (int i = 0; i < 8; ++i) acc1[i] = f32x16{};
#pragma unroll
  for (int t = 0; t < 8; ++t) {
    if (t + 2 < 8) {
      stage_tile<8, 4>(wbuf[(t + 2) % 3], u1t, 256, t + 2, tid);
      bn0 = loadB(2 * t + 4);
      bn1 = loadB(2 * t + 5);
    } else {
      stage_tile<8, 4>(wbuf[(t + 2) % 3], u2t, 256, t - 6, tid);  // gc 8,9
    }
    const h16* rb = wbuf[t % 3];
    __builtin_amdgcn_s_setprio(1);
#pragma unroll
    for (int mf = 0; mf < 8; ++mf) acc1[mf] = MFMA(ldsA(rb, mf, 0, lane), bq0, acc1[mf]);
#pragma unroll
    for (int mf = 0; mf < 8; ++mf) acc1[mf] = MFMA(ldsA(rb, mf, 1, lane), bq1, acc1[mf]);
    __builtin_amdgcn_s_setprio(0);
    bq0 = bm0; bq1 = bm1; bm0 = bn0; bm1 = bn1;
    if (t + 2 < 8) phase_sync<6>();
    else           phase_sync<4>();
  }
  unsigned hr1[8][8];
#pragma unroll
  for (int mf = 0; mf < 8; ++mf) pack_frag<true>(hr1[mf], acc1[mf], sb + 32 * mf, g);

  // ---- GEMM2: K=256 (gc 8..15)
  f32x16 acc2[8];
#pragma unroll
  for (int i = 0; i < 8; ++i) acc2[i] = f32x16{};
  gemm_hregB3<8, 8, 8, 4, 4>(acc2, hr1, u2t, 256, u3t, 256, wbuf, tid, lane);
  unsigned hr2[8][8];
#pragma unroll
  for (int mf = 0; mf < 8; ++mf) pack_frag<false>(hr2[mf], acc2[mf], sb + 256 + 32 * mf, g);

  // ---- GEMM3: K=256 (gc 16..23)
  f32x16 acc3[4];
#pragma unroll
  for (int i = 0; i < 4; ++i) acc3[i] = f32x16{};
  gemm_hregB3<4, 8, 16, 4, 4>(acc3, hr2, u3t, 256, (const h16*)nullptr, 0, wbuf, tid, lane);

  if (n < N) {
    float2* orow = (float2*)(out + (size_t)n * 128);
#pragma unroll
    for (int mf = 0; mf < 4; ++mf)
#pragma unroll
      for (int j = 0; j < 8; ++j) {
        int m = 32 * mf + 2 * (j & 1) + 8 * (j >> 1) + 4 * g;
        float2 v;
        v.x = acc3[mf][2 * j]     + sb[512 + m];
        v.y = acc3[mf][2 * j + 1] + sb[512 + m + 1];
        orow[m >> 1] = v;
      }
  }
}

// ---------------------------------------------------------------------------
// Fused prep: nodes+edges f32->f16, receiver histogram (storing each edge's
// rank = atomicAdd return), weight transpose. w1 padded to Kp=288.
// ---------------------------------------------------------------------------
struct WtArgs { const float* src[8]; h16* dst[8]; };

__global__ void k_prep_all(const float* __restrict__ nodes, const float* __restrict__ edges,
                           h16* __restrict__ nodes_h, h16* __restrict__ edges_h,
                           long n4n, long n4tot,
                           const int* __restrict__ recv, int* __restrict__ count,
                           int* __restrict__ rank, int E,
                           WtArgs a) {
  long i = (long)blockIdx.x * 256 + threadIdx.x;
  if (i < n4tot) {
    const float* src; h16* dst; long j;
    if (i < n4n) { src = nodes; dst = nodes_h; j = i; }
    else         { src = edges; dst = edges_h; j = i - n4n; }
    float4 v = ((const float4*)src)[j];
    union { h16 h[4]; uint2 u; } o;
    o.h[0] = (h16)v.x; o.h[1] = (h16)v.y; o.h[2] = (h16)v.z; o.h[3] = (h16)v.w;
    ((uint2*)dst)[j] = o.u;
  }
  if (i < E) rank[i] = atomicAdd(count + recv[i], 1);  // rank within segment
  if (i < 368640) {
    int t = (int)i;
    // seg:            w1     w2     w3     a1     a2     u1     u2     u3
    constexpr int off[9] = {0, 73728, 139264, 172032, 188416, 204800, 270336, 335872, 368640};
    constexpr int Ks[8]  = {272, 256, 256, 128, 128, 256, 256, 256};
    constexpr int Os[8]  = {256, 256, 128, 128, 128, 256, 256, 128};
    constexpr int Kp[8]  = {288, 256, 256, 128, 128, 256, 256, 256};
#pragma unroll
    for (int sgi = 0; sgi < 8; ++sgi) {
      if (t >= off[sgi] && t < off[sgi + 1]) {
        int r = t - off[sgi];
        int o = r / Kp[sgi], k = r - o * Kp[sgi];  // compile-time divisors
        a.dst[sgi][r] = (k < Ks[sgi]) ? (h16)a.src[sgi][(size_t)k * Os[sgi] + o] : (h16)0.f;
      }
    }
  }
}

// ---------------------------------------------------------------------------
// CSR: single-wave exclusive scan, int4 + 4-stream sum phase.
// count[] has 16B zeroed slack past N so the last int4 read is safe.
// ---------------------------------------------------------------------------
__global__ __launch_bounds__(64) void k_scan(const int* __restrict__ count,
                                             int* __restrict__ starts, int N) {
  int lane = threadIdx.x;
  int total4 = (N + 3) >> 2;             // int4 elements (tail zeros in slack)
  int chunk4 = (total4 + 63) >> 6;
  int lo4 = lane * chunk4;
  int hi4 = lo4 + chunk4;
  if (lo4 > total4) lo4 = total4;
  if (hi4 > total4) hi4 = total4;
  const int4* c4 = (const int4*)count;

  // 4-stream sum (independent chains for memory-level parallelism)
  int s0 = 0, s1 = 0, s2 = 0, s3 = 0;
  int i = lo4;
  for (; i + 4 <= hi4; i += 4) {
    int4 v0 = c4[i], v1 = c4[i + 1], v2 = c4[i + 2], v3 = c4[i + 3];
    s0 += v0.x + v0.y + v0.z + v0.w;
    s1 += v1.x + v1.y + v1.z + v1.w;
    s2 += v2.x + v2.y + v2.z + v2.w;
    s3 += v3.x + v3.y + v3.z + v3.w;
  }
  for (; i < hi4; ++i) {
    int4 v = c4[i];
    s0 += v.x + v.y + v.z + v.w;
  }
  int sum = s0 + s1 + s2 + s3;

  int x = sum;  // inclusive wave scan (proven shfl_up pattern)
#pragma unroll
  for (int off = 1; off < 64; off <<= 1) {
    int t = __shfl_up(x, off, 64);
    if (lane >= off) x += t;
  }
  int run = x - sum;  // exclusive prefix of this lane's chunk
  for (int j = lo4; j < hi4; ++j) {
    int4 v = c4[j];
    int4 s;
    s.x = run; run += v.x;
    s.y = run; run += v.y;
    s.z = run; run += v.z;
    s.w = run; run += v.w;
    ((int4*)starts)[j] = s;
  }
}

// ---------------------------------------------------------------------------
// Gather aggregation: one wave per node; msgs/gate are CSR-ordered, so all
// reads are contiguous streams. 2-edge ILP unroll; denom accumulated inline.
// ---------------------------------------------------------------------------
__global__ __launch_bounds__(256) void k_gather(
    const float* __restrict__ gate, const unsigned* __restrict__ segmax,
    const int* __restrict__ starts, const int* __restrict__ count,
    const h16* __restrict__ msgs_h, h16* __restrict__ aggr_h, int N)
{
  int node = (blockIdx.x * 256 + threadIdx.x) >> 6;
  int lane = threadIdx.x & 63;
  if (node >= N) return;
  int s = starts[node], c = count[node];
  float m = ordinv(segmax[node]);
  const unsigned* M = (const unsigned*)msgs_h;

  float den0 = 0.f, ax0 = 0.f, ay0 = 0.f;
  float den1 = 0.f, ax1 = 0.f, ay1 = 0.f;
  int i = 0;
  for (; i + 2 <= c; i += 2) {
    float w0 = __expf(gate[s + i]     - m);
    float w1 = __expf(gate[s + i + 1] - m);
    unsigned mv0 = M[(size_t)(s + i)     * 64 + lane];
    unsigned mv1 = M[(size_t)(s + i + 1) * 64 + lane];
    h16x2 h0 = __builtin_bit_cast(h16x2, mv0);
    h16x2 h1 = __builtin_bit_cast(h16x2, mv1);
    den0 += w0;                 den1 += w1;
    ax0 += w0 * (float)h0[0];   ax1 += w1 * (float)h1[0];
    ay0 += w0 * (float)h0[1];   ay1 += w1 * (float)h1[1];
  }
  if (i < c) {
    float w = __expf(gate[s + i] - m);
    unsigned mv = M[(size_t)(s + i) * 64 + lane];
    h16x2 hh = __builtin_bit_cast(h16x2, mv);
    den0 += w;
    ax0 += w * (float)hh[0];
    ay0 += w * (float)hh[1];
  }
  float den = den0 + den1, ax = ax0 + ax1, ay = ay0 + ay1;
  float inv = (c > 0) ? 1.f / den : 0.f;
  union { h16 h[2]; unsigned u; } o;   // RNE converts (proven numerics)
  o.h[0] = (h16)(ax * inv);
  o.h[1] = (h16)(ay * inv);
  ((unsigned*)aggr_h)[(size_t)node * 64 + lane] = o.u;
}

// ---------------------------------------------------------------------------
extern "C" void kernel_launch(void* const* d_in, const int* in_sizes, int n_in,
                              void* d_out, int out_size, void* d_ws, size_t ws_size,
                              hipStream_t stream) {
  const float* nodes  = (const float*)d_in[0];
  const float* edges  = (const float*)d_in[1];
  const int* senders  = (const int*)d_in[2];
  const int* receivers= (const int*)d_in[3];
  const float* msg_w1 = (const float*)d_in[4];  const float* msg_b1 = (const float*)d_in[5];
  const float* msg_w2 = (const float*)d_in[6];  const float* msg_b2 = (const float*)d_in[7];
  const float* msg_w3 = (const float*)d_in[8];  const float* msg_b3 = (const float*)d_in[9];
  const float* ag_w1  = (const float*)d_in[10]; const float* ag_b1  = (const float*)d_in[11];
  const float* ag_w2  = (const float*)d_in[12]; const float* ag_b2  = (const float*)d_in[13];
  const float* ag_w3  = (const float*)d_in[14]; const float* ag_b3  = (const float*)d_in[15];
  const float* up_w1  = (const float*)d_in[16]; const float* up_b1  = (const float*)d_in[17];
  const float* up_w2  = (const float*)d_in[18]; const float* up_b2  = (const float*)d_in[19];
  const float* up_w3  = (const float*)d_in[20]; const float* up_b3  = (const float*)d_in[21];

  int N = in_sizes[0] / 128;
  int E = in_sizes[2];
  float* out = (float*)d_out;

  char* ws = (char*)d_ws;
  size_t off = 0;
  auto alloc = [&](size_t bytes) -> char* {
    char* p = ws + off; off += (bytes + 255) & ~(size_t)255; return p;
  };
  h16* nodes_h = (h16*)alloc((size_t)N * 128 * 2);
  h16* edges_h = (h16*)alloc((size_t)E * 16 * 2);
  h16* w1t = (h16*)alloc(256 * 288 * 2);
  h16* w2t = (h16*)alloc(256 * 256 * 2);
  h16* w3t = (h16*)alloc(128 * 256 * 2);
  h16* a1t = (h16*)alloc(128 * 128 * 2);
  h16* a2t = (h16*)alloc(128 * 128 * 2);
  h16* u1t = (h16*)alloc(256 * 256 * 2);
  h16* u2t = (h16*)alloc(256 * 256 * 2);
  h16* u3t = (h16*)alloc(128 * 256 * 2);
  h16* msgs_h = (h16*)alloc((size_t)E * 128 * 2);
  float* gate = (float*)alloc((size_t)E * 4);
  // segmax and count adjacent -> one memset covers both (+16B slack for int4 scan)
  unsigned* segmax = (unsigned*)alloc((size_t)N * 8 + 16);
  int* count  = (int*)(segmax + N);
  int* starts = (int*)alloc((size_t)N * 4 + 16);
  int* rank   = (int*)alloc((size_t)E * 4);
  h16* aggr_h = (h16*)alloc((size_t)N * 128 * 2);

  hipMemsetAsync(segmax, 0, (size_t)N * 8 + 16, stream);

  WtArgs wa;
  wa.src[0] = msg_w1; wa.dst[0] = w1t;
  wa.src[1] = msg_w2; wa.dst[1] = w2t;
  wa.src[2] = msg_w3; wa.dst[2] = w3t;
  wa.src[3] = ag_w1;  wa.dst[3] = a1t;
  wa.src[4] = ag_w2;  wa.dst[4] = a2t;
  wa.src[5] = up_w1;  wa.dst[5] = u1t;
  wa.src[6] = up_w2;  wa.dst[6] = u2t;
  wa.src[7] = up_w3;  wa.dst[7] = u3t;

  // fused converts + histogram (rank) + weight transpose
  long n4n = (long)N * 128 / 4, n4e = (long)E * 16 / 4;
  long n4tot = n4n + n4e;
  long gmax = n4tot;  // n4tot (2.05M) > E (400k) > 368640
  k_prep_all<<<(int)((gmax + 255) / 256), 256, 0, stream>>>(
      nodes, edges, nodes_h, edges_h, n4n, n4tot, receivers, count, rank, E, wa);

  // CSR segment starts
  k_scan<<<1, 64, 0, stream>>>(count, starts, N);

  // fused edge pipeline (msgs + gate at starts[re]+rank[e], segmax)
  k_edge<<<(E + 127) / 128, 256, 0, stream>>>(
      nodes_h, edges_h, senders, receivers, starts, rank, w1t, w2t, w3t, a1t, a2t,
      msg_b1, msg_b2, msg_b3, ag_b1, ag_b2, ag_w3, ag_b3,
      msgs_h, gate, segmax, E);

  // streaming segment softmax + aggregation
  k_gather<<<(int)(((size_t)N * 64 + 255) / 256), 256, 0, stream>>>(
      gate, segmax, starts, count, msgs_h, aggr_h, N);

  // node update
  k_update<<<(N + 127) / 128, 256, 0, stream>>>(
      nodes_h, aggr_h, u1t, u2t, u3t, up_b1, up_b2, up_b3, out, N);
}

// Round 14
// 340.678 us; speedup vs baseline: 1.0670x; 1.0670x over previous
//
#include <hip/hip_runtime.h>
#include <stdint.h>

// ---------------------------------------------------------------------------
// GNN layer, MI355X (gfx950). All GEMMs via v_mfma_f32_32x32x16_f16, fp32 acc.
// Transposed formulation: C^T[out][edge] = W^T[out][k] @ feats^T[k][edge].
// Each wave owns 32 edges (cols) x full output width (8 or 4 32-row m-frags).
// Inter-layer activation handoff in registers via cvt_pkrtz + permlane32_swap.
//
// Round 14 = round 12 verbatim (proven best: 340.8us, absmax 0.015625).
// Round 13's counted-vmcnt pipeline (T4) REVERTED: -9% (227->248us k_edge),
// reproducing the documented m131-m141 result -- sched_barrier+manual waitcnt
// defeats the compiler's scheduling on 2-barrier-per-tile structures.
// Falsified levers for k_edge (do not retry): fewer barriers (R11 null),
// 8-wave blocks (R6 worse: 1 block/CU), counted vmcnt (R13 -9%).
// Quarantined patterns: BK=64 retile (R5), in-kernel divergent atomic slot
// claim + shfl broadcast (R9), 1024-thread hierarchical scan (R2).
// ---------------------------------------------------------------------------

typedef _Float16 h16;
typedef _Float16 half8  __attribute__((ext_vector_type(8)));
typedef _Float16 h16x2  __attribute__((ext_vector_type(2)));
typedef float    f32x16 __attribute__((ext_vector_type(16)));
typedef unsigned u32x4  __attribute__((ext_vector_type(4)));

__device__ __forceinline__ f32x16 MFMA(half8 a, half8 b, f32x16 c) {
  return __builtin_amdgcn_mfma_f32_32x32x16_f16(a, b, c, 0, 0, 0);
}

// v_permlane32_swap_b32: new_a = [a_lo | b_lo], new_b = [a_hi | b_hi]
__device__ __forceinline__ void lane_swap(unsigned &a, unsigned &b) {
  asm volatile("v_permlane32_swap_b32 %0, %1" : "+v"(a), "+v"(b));
}

// order-preserving float->uint map (atomicMax-able), init = 0
__device__ __forceinline__ unsigned ordf(float f) {
  unsigned b = __float_as_uint(f);
  return (b & 0x80000000u) ? ~b : (b | 0x80000000u);
}
__device__ __forceinline__ float ordinv(unsigned u) {
  return __uint_as_float((u & 0x80000000u) ? (u ^ 0x80000000u) : ~u);
}

// Stage one weight tile [R=32*MFA rows][32 k] f16 into LDS via global_load_lds.
// LDS layout: row-major 64B rows, 16B chunk index XOR-swizzled with (row>>1)&3
// (pre-swizzled on the GLOBAL source; LDS dest stays linear per G21).
template<int MFA, int WAVES>
__device__ __forceinline__ void stage_tile(h16* dst, const h16* wT, int K, int kt, int tid) {
  int wv = tid >> 6, lane = tid & 63;
  static_assert((MFA * 2) % WAVES == 0, "tile chunks must divide evenly");
#pragma unroll
  for (int it = 0; it < (MFA * 2) / WAVES; ++it) {
    int slotbase = it * (WAVES * 64) + wv * 64;  // wave-uniform
    int s = slotbase + lane;
    int row = s >> 2, x = s & 3;
    int c = x ^ ((row >> 1) & 3);
    const h16* src = wT + (size_t)row * K + kt * 32 + c * 8;
    h16* d = dst + slotbase * 8;                 // wave-uniform base; lane*16B implicit
    __builtin_amdgcn_global_load_lds((const __attribute__((address_space(1))) unsigned*)src,
                                     (__attribute__((address_space(3))) unsigned*)d, 16, 0, 0);
  }
}

// A-frag read: lane holds W^T[32*mf + (lane&31)][16*ksl + 8*(lane>>5) + i]
__device__ __forceinline__ half8 ldsA(const h16* buf, int mf, int ksl, int lane) {
  int r31 = lane & 31, g = lane >> 5;
  int c = (2 * ksl + g) ^ ((r31 >> 1) & 3);
  return *(const half8*)(buf + mf * 1024 + r31 * 32 + c * 8);
}

// acc(16 f32, D-layout row=(r&3)+8*(r>>2)+4g) + bias [-> relu] -> 8x packed f16
template<bool RELU>
__device__ __forceinline__ void pack_frag(unsigned* hr, const f32x16 a, const float* bias, int g) {
#pragma unroll
  for (int j = 0; j < 8; ++j) {
    int m = 2 * (j & 1) + 8 * (j >> 1) + 4 * g;
    float x = a[2 * j]     + bias[m];
    float y = a[2 * j + 1] + bias[m + 1];
    if (RELU) { x = fmaxf(x, 0.f); y = fmaxf(y, 0.f); }
    auto p = __builtin_amdgcn_cvt_pkrtz(x, y);
    hr[j] = __builtin_bit_cast(unsigned, p);
  }
}

// Build next-GEMM B-frag (k = 16*ks + 8g + i) from packed hregs of this K-tile.
// swap(v_p, u_p) -> (B[p], B[p+2]); ks = 2*kt + ksl, v_p=hr[4ksl+p], u_p=hr[4ksl+2+p]
__device__ __forceinline__ half8 buildB(unsigned* hr, int ksl) {
  unsigned v0 = hr[4 * ksl + 0], v1 = hr[4 * ksl + 1];
  unsigned u0 = hr[4 * ksl + 2], u1 = hr[4 * ksl + 3];
  lane_swap(v0, u0);
  lane_swap(v1, u1);
  u32x4 t = {v0, v1, u0, u1};
  return __builtin_bit_cast(half8, t);
}

// Generic GEMM with B sourced from hregs; 4-buffer rotation, 2 tiles/phase.
// GB = global tile counter base; buffer = (global counter) & 3. At the end,
// stages tiles 0,1 of the next GEMM's weights (global GB+KT, GB+KT+1).
template<int MFA, int KT, int GB, int NMFA, int WAVES>
__device__ __forceinline__ void gemm_hregB2(f32x16* acc, unsigned (*hreg)[8],
    const h16* wT, int K, const h16* nW, int nK,
    h16 (*wbuf)[8192], int tid, int lane) {
  static_assert(KT % 2 == 0, "KT must be even");
#pragma unroll
  for (int q = 0; q < KT / 2; ++q) {
    __syncthreads();
    if (2 * q + 2 < KT) {
      stage_tile<MFA, WAVES>(wbuf[(GB + 2 * q + 2) & 3], wT, K, 2 * q + 2, tid);
      stage_tile<MFA, WAVES>(wbuf[(GB + 2 * q + 3) & 3], wT, K, 2 * q + 3, tid);
    } else if (nW) {
      stage_tile<NMFA, WAVES>(wbuf[(GB + KT) & 3], nW, nK, 0, tid);
      stage_tile<NMFA, WAVES>(wbuf[(GB + KT + 1) & 3], nW, nK, 1, tid);
    }
    __builtin_amdgcn_s_setprio(1);
#pragma unroll
    for (int tt = 0; tt < 2; ++tt) {
      int t = 2 * q + tt;
      const h16* rb = wbuf[(GB + t) & 3];
#pragma unroll
      for (int ksl = 0; ksl < 2; ++ksl) {
        half8 b = buildB(hreg[t], ksl);
#pragma unroll
        for (int mf = 0; mf < MFA; ++mf)
          acc[mf] = MFMA(ldsA(rb, mf, ksl, lane), b, acc[mf]);
      }
    }
    __builtin_amdgcn_s_setprio(0);
  }
}

// ---------------------------------------------------------------------------
// Edge kernel: feats(272->pad 320) -> msg MLP -> msgs(128) -> gate MLP -> gate
// 256 threads = 4 waves x 32 edges = 128 edges/block. 17 barrier phases.
// CSR slot computed arithmetically: pidx = starts[re] + rank[e].
// Global tile counters: GEMM1 w1t 0..9, GEMM2 w2t 10..17, GEMM3 w3t 18..25,
// GEMM4 a1t 26..29, GEMM5 a2t 30..33. Buffer = counter & 3.
// ---------------------------------------------------------------------------
__global__ __launch_bounds__(256, 2) void k_edge(
    const h16* __restrict__ nodes_h, const h16* __restrict__ edges_h,
    const int* __restrict__ senders, const int* __restrict__ receivers,
    const int* __restrict__ starts, const int* __restrict__ rank,
    const h16* __restrict__ w1t, const h16* __restrict__ w2t, const h16* __restrict__ w3t,
    const h16* __restrict__ a1t, const h16* __restrict__ a2t,
    const float* __restrict__ b1, const float* __restrict__ b2, const float* __restrict__ b3,
    const float* __restrict__ ab1, const float* __restrict__ ab2,
    const float* __restrict__ ag3, const float* __restrict__ ab3,
    h16* __restrict__ msgs_h, float* __restrict__ gate, unsigned* __restrict__ segmax, int E)
{
  __shared__ h16 wbuf[4][8192];   // 4 x 16KB weight tiles (2 in compute, 2 staging)
  __shared__ float sb[1025];      // biases + ag_w3

  int tid = threadIdx.x, lane = tid & 63, wv = tid >> 6;
  int g = lane >> 5, c31 = lane & 31;

  sb[tid] = b1[tid];
  sb[256 + tid] = b2[tid];
  if (tid < 128) {
    sb[512 + tid] = b3[tid];
    sb[640 + tid] = ab1[tid];
    sb[768 + tid] = ab2[tid];
    sb[896 + tid] = ag3[tid];
  }
  if (tid == 0) sb[1024] = ab3[0];

  int e = blockIdx.x * 128 + wv * 32 + c31;
  bool ev = (e < E);
  int ec = ev ? e : (E - 1);
  int se = senders[ec], re = receivers[ec];
  int pidx = starts[re] + rank[ec];   // CSR slot (rank from prep's histogram)
  const h16* pe = edges_h + (size_t)ec * 16;
  const h16* ps = nodes_h + (size_t)se * 128;
  const h16* pr = nodes_h + (size_t)re * 128;

  // prologue: stage tiles 0,1 of w1t (global counters 0,1 -> bufs 0,1)
  stage_tile<8, 4>(wbuf[0], w1t, 320, 0, tid);
  stage_tile<8, 4>(wbuf[1], w1t, 320, 1, tid);

  // feats^T B-frag, 16-wide slice ks: 0=edge, 1..8=sender, 9..16=receiver, 17+=pad
  auto loadB1 = [&](int ks) -> half8 {
    if (ks >= 17) { half8 z = {}; return z; }
    const h16* base = (ks == 0) ? pe : (ks < 9) ? (ps + 16 * ks - 16) : (pr + 16 * ks - 144);
    return *(const half8*)(base + 8 * g);
  };

  // ---- GEMM1: h1^T[256][32e] = W1^T @ feats^T, Kp=320 (10 tiles, gc 0..9)
  f32x16 acc1[8];
#pragma unroll
  for (int i = 0; i < 8; ++i) acc1[i] = f32x16{};
  half8 bq[4], bn[4];
#pragma unroll
  for (int s = 0; s < 4; ++s) bq[s] = loadB1(s);   // slices of tiles 0,1
#pragma unroll
  for (int q = 0; q < 5; ++q) {
    __syncthreads();
    if (q < 4) {
      stage_tile<8, 4>(wbuf[(2 * q + 2) & 3], w1t, 320, 2 * q + 2, tid);
      stage_tile<8, 4>(wbuf[(2 * q + 3) & 3], w1t, 320, 2 * q + 3, tid);
#pragma unroll
      for (int s = 0; s < 4; ++s) bn[s] = loadB1(4 * q + 4 + s);
    } else {
      stage_tile<8, 4>(wbuf[2], w2t, 256, 0, tid);  // gc 10 -> buf 2
      stage_tile<8, 4>(wbuf[3], w2t, 256, 1, tid);  // gc 11 -> buf 3
    }
    __builtin_amdgcn_s_setprio(1);
#pragma unroll
    for (int tt = 0; tt < 2; ++tt) {
      const h16* rb = wbuf[(2 * q + tt) & 3];
#pragma unroll
      for (int ksl = 0; ksl < 2; ++ksl) {
        half8 b = bq[2 * tt + ksl];
#pragma unroll
        for (int mf = 0; mf < 8; ++mf)
          acc1[mf] = MFMA(ldsA(rb, mf, ksl, lane), b, acc1[mf]);
      }
    }
    __builtin_amdgcn_s_setprio(0);
#pragma unroll
    for (int s = 0; s < 4; ++s) bq[s] = bn[s];
  }
  unsigned hreg1[8][8];
#pragma unroll
  for (int mf = 0; mf < 8; ++mf) pack_frag<true>(hreg1[mf], acc1[mf], sb + 32 * mf, g);

  // ---- GEMM2: h2^T = W2^T @ h1^T, K=256 (gc 10..17)
  f32x16 acc2[8];
#pragma unroll
  for (int i = 0; i < 8; ++i) acc2[i] = f32x16{};
  gemm_hregB2<8, 8, 10, 4, 4>(acc2, hreg1, w2t, 256, w3t, 256, wbuf, tid, lane);
  unsigned hreg2[8][8];
#pragma unroll
  for (int mf = 0; mf < 8; ++mf) pack_frag<false>(hreg2[mf], acc2[mf], sb + 256 + 32 * mf, g);

  // ---- GEMM3: msgs^T[128][32e] = W3^T @ h2^T, K=256 (gc 18..25)
  f32x16 acc3[4];
#pragma unroll
  for (int i = 0; i < 4; ++i) acc3[i] = f32x16{};
  gemm_hregB2<4, 8, 18, 4, 4>(acc3, hreg2, w3t, 256, a1t, 128, wbuf, tid, lane);
  unsigned hreg3[4][8];
  unsigned* mrow = (unsigned*)(msgs_h + (size_t)pidx * 128);
#pragma unroll
  for (int mf = 0; mf < 4; ++mf) {
    pack_frag<false>(hreg3[mf], acc3[mf], sb + 512 + 32 * mf, g);
    if (ev) {
#pragma unroll
      for (int j = 0; j < 8; ++j)
        mrow[16 * mf + (j & 1) + 4 * (j >> 1) + 2 * g] = hreg3[mf][j];
    }
  }

  // ---- GEMM4: g1^T = Ag1^T @ msgs^T, K=128 (gc 26..29)
  f32x16 acc4[4];
#pragma unroll
  for (int i = 0; i < 4; ++i) acc4[i] = f32x16{};
  gemm_hregB2<4, 4, 26, 4, 4>(acc4, hreg3, a1t, 128, a2t, 128, wbuf, tid, lane);
  unsigned hreg4[4][8];
#pragma unroll
  for (int mf = 0; mf < 4; ++mf) pack_frag<true>(hreg4[mf], acc4[mf], sb + 640 + 32 * mf, g);

  // ---- GEMM5: g2^T = Ag2^T @ g1^T, K=128 (gc 30..33)
  f32x16 acc5[4];
#pragma unroll
  for (int i = 0; i < 4; ++i) acc5[i] = f32x16{};
  gemm_hregB2<4, 4, 30, 4, 4>(acc5, hreg4, a2t, 128, (const h16*)nullptr, 0, wbuf, tid, lane);

  // ---- gate = (g2 + ab2) . ag_w3 + ab3, stored at pidx
  float gs = 0.f;
#pragma unroll
  for (int mf = 0; mf < 4; ++mf)
#pragma unroll
    for (int r = 0; r < 16; ++r) {
      int m = 32 * mf + (r & 3) + 8 * (r >> 2) + 4 * g;
      gs += (acc5[mf][r] + sb[768 + m]) * sb[896 + m];
    }
  unsigned xa = __float_as_uint(gs), xb = xa;
  lane_swap(xa, xb);  // xa = lo-half gs for all, xb = hi-half gs for all
  float tot = __uint_as_float(xa) + __uint_as_float(xb) + sb[1024];
  if (lane < 32 && ev) {
    gate[pidx] = tot;
    atomicMax(segmax + re, ordf(tot));
  }
}

// ---------------------------------------------------------------------------
// Update kernel: [nodes | aggr](256) -> update MLP -> out(128) fp32
// 256 threads = 4 waves x 32 nodes = 128 nodes/block. 12 barrier phases.
// Global tile counters: GEMM1 u1t 0..7, GEMM2 u2t 8..15, GEMM3 u3t 16..23.
// ---------------------------------------------------------------------------
__global__ __launch_bounds__(256, 2) void k_update(
    const h16* __restrict__ nodes_h, const h16* __restrict__ aggr_h,
    const h16* __restrict__ u1t, const h16* __restrict__ u2t, const h16* __restrict__ u3t,
    const float* __restrict__ b1, const float* __restrict__ b2, const float* __restrict__ b3,
    float* __restrict__ out, int N)
{
  __shared__ h16 wbuf[4][8192];
  __shared__ float sb[640];
  int tid = threadIdx.x, lane = tid & 63, wv = tid >> 6;
  int g = lane >> 5, c31 = lane & 31;
  sb[tid] = b1[tid];
  sb[256 + tid] = b2[tid];
  if (tid < 128) sb[512 + tid] = b3[tid];

  int n = blockIdx.x * 128 + wv * 32 + c31;
  int nc = (n < N) ? n : (N - 1);
  const h16* pn = nodes_h + (size_t)nc * 128;
  const h16* pa = aggr_h + (size_t)nc * 128;
  auto loadB = [&](int ks) -> half8 {
    const h16* base = (ks < 8) ? (pn + 16 * ks) : (pa + 16 * ks - 128);
    return *(const half8*)(base + 8 * g);
  };

  // prologue: stage tiles 0,1 of u1t (gc 0,1 -> bufs 0,1)
  stage_tile<8, 4>(wbuf[0], u1t, 256, 0, tid);
  stage_tile<8, 4>(wbuf[1], u1t, 256, 1, tid);

  f32x16 acc1[8];
#pragma unroll
  for (int i = 0; i < 8; ++i) acc1[i] = f32x16{};
  half8 bq[4], bn[4];
#pragma unroll
  for (int s = 0; s < 4; ++s) bq[s] = loadB(s);
#pragma unroll
  for (int q = 0; q < 4; ++q) {
    __syncthreads();
    if (q < 3) {
      stage_tile<8, 4>(wbuf[(2 * q + 2) & 3], u1t, 256, 2 * q + 2, tid);
      stage_tile<8, 4>(wbuf[(2 * q + 3) & 3], u1t, 256, 2 * q + 3, tid);
#pragma unroll
      for (int s = 0; s < 4; ++s) bn[s] = loadB(4 * q + 4 + s);
    } else {
      stage_tile<8, 4>(wbuf[0], u2t, 256, 0, tid);  // gc 8 -> buf 0
      stage_tile<8, 4>(wbuf[1], u2t, 256, 1, tid);  // gc 9 -> buf 1
    }
    __builtin_amdgcn_s_setprio(1);
#pragma unroll
    for (int tt = 0; tt < 2; ++tt) {
      const h16* rb = wbuf[(2 * q + tt) & 3];
#pragma unroll
      for (int ksl = 0; ksl < 2; ++ksl) {
        half8 b = bq[2 * tt + ksl];
#pragma unroll
        for (int mf = 0; mf < 8; ++mf)
          acc1[mf] = MFMA(ldsA(rb, mf, ksl, lane), b, acc1[mf]);
      }
    }
    __builtin_amdgcn_s_setprio(0);
#pragma unroll
    for (int s = 0; s < 4; ++s) bq[s] = bn[s];
  }
  unsigned hr1[8][8];
#pragma unroll
  for (int mf = 0; mf < 8; ++mf) pack_frag<true>(hr1[mf], acc1[mf], sb + 32 * mf, g);

  // ---- GEMM2: K=256 (gc 8..15)
  f32x16 acc2[8];
#pragma unroll
  for (int i = 0; i < 8; ++i) acc2[i] = f32x16{};
  gemm_hregB2<8, 8, 8, 4, 4>(acc2, hr1, u2t, 256, u3t, 256, wbuf, tid, lane);
  unsigned hr2[8][8];
#pragma unroll
  for (int mf = 0; mf < 8; ++mf) pack_frag<false>(hr2[mf], acc2[mf], sb + 256 + 32 * mf, g);

  // ---- GEMM3: K=256 (gc 16..23)
  f32x16 acc3[4];
#pragma unroll
  for (int i = 0; i < 4; ++i) acc3[i] = f32x16{};
  gemm_hregB2<4, 8, 16, 4, 4>(acc3, hr2, u3t, 256, (const h16*)nullptr, 0, wbuf, tid, lane);

  if (n < N) {
    float2* orow = (float2*)(out + (size_t)n * 128);
#pragma unroll
    for (int mf = 0; mf < 4; ++mf)
#pragma unroll
      for (int j = 0; j < 8; ++j) {
        int m = 32 * mf + 2 * (j & 1) + 8 * (j >> 1) + 4 * g;
        float2 v;
        v.x = acc3[mf][2 * j]     + sb[512 + m];
        v.y = acc3[mf][2 * j + 1] + sb[512 + m + 1];
        orow[m >> 1] = v;
      }
  }
}

// ---------------------------------------------------------------------------
// Fused prep: nodes+edges f32->f16, receiver histogram (storing each edge's
// rank = atomicAdd return), weight transpose. w1 padded to Kp=320.
// ---------------------------------------------------------------------------
struct WtArgs { const float* src[8]; h16* dst[8]; };

__global__ void k_prep_all(const float* __restrict__ nodes, const float* __restrict__ edges,
                           h16* __restrict__ nodes_h, h16* __restrict__ edges_h,
                           long n4n, long n4tot,
                           const int* __restrict__ recv, int* __restrict__ count,
                           int* __restrict__ rank, int E,
                           WtArgs a) {
  long i = (long)blockIdx.x * 256 + threadIdx.x;
  if (i < n4tot) {
    const float* src; h16* dst; long j;
    if (i < n4n) { src = nodes; dst = nodes_h; j = i; }
    else         { src = edges; dst = edges_h; j = i - n4n; }
    float4 v = ((const float4*)src)[j];
    union { h16 h[4]; uint2 u; } o;
    o.h[0] = (h16)v.x; o.h[1] = (h16)v.y; o.h[2] = (h16)v.z; o.h[3] = (h16)v.w;
    ((uint2*)dst)[j] = o.u;
  }
  if (i < E) rank[i] = atomicAdd(count + recv[i], 1);  // rank within segment
  if (i < 376832) {
    int t = (int)i;
    // seg:            w1     w2     w3     a1     a2     u1     u2     u3
    constexpr int off[9] = {0, 81920, 147456, 180224, 196608, 212992, 278528, 344064, 376832};
    constexpr int Ks[8]  = {272, 256, 256, 128, 128, 256, 256, 256};
    constexpr int Os[8]  = {256, 256, 128, 128, 128, 256, 256, 128};
    constexpr int Kp[8]  = {320, 256, 256, 128, 128, 256, 256, 256};
#pragma unroll
    for (int sgi = 0; sgi < 8; ++sgi) {
      if (t >= off[sgi] && t < off[sgi + 1]) {
        int r = t - off[sgi];
        int o = r / Kp[sgi], k = r - o * Kp[sgi];  // compile-time divisors
        a.dst[sgi][r] = (k < Ks[sgi]) ? (h16)a.src[sgi][(size_t)k * Os[sgi] + o] : (h16)0.f;
      }
    }
  }
}

// ---------------------------------------------------------------------------
// CSR: single-wave exclusive scan, int4 + 4-stream sum phase.
// count[] has 16B zeroed slack past N so the last int4 read is safe.
// ---------------------------------------------------------------------------
__global__ __launch_bounds__(64) void k_scan(const int* __restrict__ count,
                                             int* __restrict__ starts, int N) {
  int lane = threadIdx.x;
  int total4 = (N + 3) >> 2;             // int4 elements (tail zeros in slack)
  int chunk4 = (total4 + 63) >> 6;
  int lo4 = lane * chunk4;
  int hi4 = lo4 + chunk4;
  if (lo4 > total4) lo4 = total4;
  if (hi4 > total4) hi4 = total4;
  const int4* c4 = (const int4*)count;

  // 4-stream sum (independent chains for memory-level parallelism)
  int s0 = 0, s1 = 0, s2 = 0, s3 = 0;
  int i = lo4;
  for (; i + 4 <= hi4; i += 4) {
    int4 v0 = c4[i], v1 = c4[i + 1], v2 = c4[i + 2], v3 = c4[i + 3];
    s0 += v0.x + v0.y + v0.z + v0.w;
    s1 += v1.x + v1.y + v1.z + v1.w;
    s2 += v2.x + v2.y + v2.z + v2.w;
    s3 += v3.x + v3.y + v3.z + v3.w;
  }
  for (; i < hi4; ++i) {
    int4 v = c4[i];
    s0 += v.x + v.y + v.z + v.w;
  }
  int sum = s0 + s1 + s2 + s3;

  int x = sum;  // inclusive wave scan (proven shfl_up pattern)
#pragma unroll
  for (int off = 1; off < 64; off <<= 1) {
    int t = __shfl_up(x, off, 64);
    if (lane >= off) x += t;
  }
  int run = x - sum;  // exclusive prefix of this lane's chunk
  for (int j = lo4; j < hi4; ++j) {
    int4 v = c4[j];
    int4 s;
    s.x = run; run += v.x;
    s.y = run; run += v.y;
    s.z = run; run += v.z;
    s.w = run; run += v.w;
    ((int4*)starts)[j] = s;
  }
}

// ---------------------------------------------------------------------------
// Gather aggregation: one wave per node; msgs/gate are CSR-ordered, so all
// reads are contiguous streams. 2-edge ILP unroll; denom accumulated inline.
// ---------------------------------------------------------------------------
__global__ __launch_bounds__(256) void k_gather(
    const float* __restrict__ gate, const unsigned* __restrict__ segmax,
    const int* __restrict__ starts, const int* __restrict__ count,
    const h16* __restrict__ msgs_h, h16* __restrict__ aggr_h, int N)
{
  int node = (blockIdx.x * 256 + threadIdx.x) >> 6;
  int lane = threadIdx.x & 63;
  if (node >= N) return;
  int s = starts[node], c = count[node];
  float m = ordinv(segmax[node]);
  const unsigned* M = (const unsigned*)msgs_h;

  float den0 = 0.f, ax0 = 0.f, ay0 = 0.f;
  float den1 = 0.f, ax1 = 0.f, ay1 = 0.f;
  int i = 0;
  for (; i + 2 <= c; i += 2) {
    float w0 = __expf(gate[s + i]     - m);
    float w1 = __expf(gate[s + i + 1] - m);
    unsigned mv0 = M[(size_t)(s + i)     * 64 + lane];
    unsigned mv1 = M[(size_t)(s + i + 1) * 64 + lane];
    h16x2 h0 = __builtin_bit_cast(h16x2, mv0);
    h16x2 h1 = __builtin_bit_cast(h16x2, mv1);
    den0 += w0;                 den1 += w1;
    ax0 += w0 * (float)h0[0];   ax1 += w1 * (float)h1[0];
    ay0 += w0 * (float)h0[1];   ay1 += w1 * (float)h1[1];
  }
  if (i < c) {
    float w = __expf(gate[s + i] - m);
    unsigned mv = M[(size_t)(s + i) * 64 + lane];
    h16x2 hh = __builtin_bit_cast(h16x2, mv);
    den0 += w;
    ax0 += w * (float)hh[0];
    ay0 += w * (float)hh[1];
  }
  float den = den0 + den1, ax = ax0 + ax1, ay = ay0 + ay1;
  float inv = (c > 0) ? 1.f / den : 0.f;
  union { h16 h[2]; unsigned u; } o;   // RNE converts (proven numerics)
  o.h[0] = (h16)(ax * inv);
  o.h[1] = (h16)(ay * inv);
  ((unsigned*)aggr_h)[(size_t)node * 64 + lane] = o.u;
}

// ---------------------------------------------------------------------------
extern "C" void kernel_launch(void* const* d_in, const int* in_sizes, int n_in,
                              void* d_out, int out_size, void* d_ws, size_t ws_size,
                              hipStream_t stream) {
  const float* nodes  = (const float*)d_in[0];
  const float* edges  = (const float*)d_in[1];
  const int* senders  = (const int*)d_in[2];
  const int* receivers= (const int*)d_in[3];
  const float* msg_w1 = (const float*)d_in[4];  const float* msg_b1 = (const float*)d_in[5];
  const float* msg_w2 = (const float*)d_in[6];  const float* msg_b2 = (const float*)d_in[7];
  const float* msg_w3 = (const float*)d_in[8];  const float* msg_b3 = (const float*)d_in[9];
  const float* ag_w1  = (const float*)d_in[10]; const float* ag_b1  = (const float*)d_in[11];
  const float* ag_w2  = (const float*)d_in[12]; const float* ag_b2  = (const float*)d_in[13];
  const float* ag_w3  = (const float*)d_in[14]; const float* ag_b3  = (const float*)d_in[15];
  const float* up_w1  = (const float*)d_in[16]; const float* up_b1  = (const float*)d_in[17];
  const float* up_w2  = (const float*)d_in[18]; const float* up_b2  = (const float*)d_in[19];
  const float* up_w3  = (const float*)d_in[20]; const float* up_b3  = (const float*)d_in[21];

  int N = in_sizes[0] / 128;
  int E = in_sizes[2];
  float* out = (float*)d_out;

  char* ws = (char*)d_ws;
  size_t off = 0;
  auto alloc = [&](size_t bytes) -> char* {
    char* p = ws + off; off += (bytes + 255) & ~(size_t)255; return p;
  };
  h16* nodes_h = (h16*)alloc((size_t)N * 128 * 2);
  h16* edges_h = (h16*)alloc((size_t)E * 16 * 2);
  h16* w1t = (h16*)alloc(256 * 320 * 2);
  h16* w2t = (h16*)alloc(256 * 256 * 2);
  h16* w3t = (h16*)alloc(128 * 256 * 2);
  h16* a1t = (h16*)alloc(128 * 128 * 2);
  h16* a2t = (h16*)alloc(128 * 128 * 2);
  h16* u1t = (h16*)alloc(256 * 256 * 2);
  h16* u2t = (h16*)alloc(256 * 256 * 2);
  h16* u3t = (h16*)alloc(128 * 256 * 2);
  h16* msgs_h = (h16*)alloc((size_t)E * 128 * 2);
  float* gate = (float*)alloc((size_t)E * 4);
  // segmax and count adjacent -> one memset covers both (+16B slack for int4 scan)
  unsigned* segmax = (unsigned*)alloc((size_t)N * 8 + 16);
  int* count  = (int*)(segmax + N);
  int* starts = (int*)alloc((size_t)N * 4 + 16);
  int* rank   = (int*)alloc((size_t)E * 4);
  h16* aggr_h = (h16*)alloc((size_t)N * 128 * 2);

  hipMemsetAsync(segmax, 0, (size_t)N * 8 + 16, stream);

  WtArgs wa;
  wa.src[0] = msg_w1; wa.dst[0] = w1t;
  wa.src[1] = msg_w2; wa.dst[1] = w2t;
  wa.src[2] = msg_w3; wa.dst[2] = w3t;
  wa.src[3] = ag_w1;  wa.dst[3] = a1t;
  wa.src[4] = ag_w2;  wa.dst[4] = a2t;
  wa.src[5] = up_w1;  wa.dst[5] = u1t;
  wa.src[6] = up_w2;  wa.dst[6] = u2t;
  wa.src[7] = up_w3;  wa.dst[7] = u3t;

  // fused converts + histogram (rank) + weight transpose
  long n4n = (long)N * 128 / 4, n4e = (long)E * 16 / 4;
  long n4tot = n4n + n4e;
  long gmax = n4tot;  // n4tot (2.05M) > E (400k) > 376832
  k_prep_all<<<(int)((gmax + 255) / 256), 256, 0, stream>>>(
      nodes, edges, nodes_h, edges_h, n4n, n4tot, receivers, count, rank, E, wa);

  // CSR segment starts
  k_scan<<<1, 64, 0, stream>>>(count, starts, N);

  // fused edge pipeline (msgs + gate at starts[re]+rank[e], segmax)
  k_edge<<<(E + 127) / 128, 256, 0, stream>>>(
      nodes_h, edges_h, senders, receivers, starts, rank, w1t, w2t, w3t, a1t, a2t,
      msg_b1, msg_b2, msg_b3, ag_b1, ag_b2, ag_w3, ag_b3,
      msgs_h, gate, segmax, E);

  // streaming segment softmax + aggregation
  k_gather<<<(int)(((size_t)N * 64 + 255) / 256), 256, 0, stream>>>(
      gate, segmax, starts, count, msgs_h, aggr_h, N);

  // node update
  k_update<<<(N + 127) / 128, 256, 0, stream>>>(
      nodes_h, aggr_h, u1t, u2t, u3t, up_b1, up_b2, up_b3, out, N);
}